// Round 9
// baseline (296.656 us; speedup 1.0000x reference)
//
#include <hip/hip_runtime.h>
#include <hip/hip_fp16.h>
#include <stdint.h>

// LRU single-step collapsed:  y = u @ M^T + y0
//   M  = 2*(C_re G B_re - C_im G B_im) + D,  y0 = 2*(C_re c_re - C_im c_im), c = lam*x
// f16 MFMA, scaled hi/lo splits (x256 keeps lo-parts f16-normal).
// M-build: 128^2-tile split-K, 2-product (C_hi * (Bh+Bl)), fp32 partials (NO atomics).
// Main: 128^2 m97-structure, 2-product (u_hi(RTN) * (Mh+Ml)), epilogue /256 + y0.

typedef _Float16 f16x8 __attribute__((ext_vector_type(8)));
typedef float f32x4 __attribute__((ext_vector_type(4)));

#define GLOBAL_AS __attribute__((address_space(1)))
#define LDS_AS __attribute__((address_space(3)))

constexpr int BATCH = 16384, DIN = 1024, DSTATE = 2048, DOUT = 1024;
constexpr int S2 = 2 * DSTATE;  // 4096

// Rows are 32 f16 = 64B = 4 x 16B slots; XOR-swizzle slot by ((row>>1)&3).
// Verified: SQ_LDS_BANK_CONFLICT == 0 (R1/R3/R6).
__device__ __forceinline__ int lds_off(int row, int k) {
  int slot = k >> 3;
  int sl = slot ^ ((row >> 1) & 3);
  return row * 64 + sl * 16 + (k & 7) * 2;
}

// ---------------- Bgt[i][s2] = 256*exp(ga[s])*B[s][i], transposed, f16 hi/lo ----------------
__global__ void k_bgt(const float* __restrict__ Bre, const float* __restrict__ Bim,
                      const float* __restrict__ ga, __half* __restrict__ Bh,
                      __half* __restrict__ Bl) {
  __shared__ float tile[32][33];
  int s0 = blockIdx.x * 32, i0 = blockIdx.y * 32;
  int c = threadIdx.x & 31, r0 = threadIdx.x >> 5;  // 8 rows per pass
  const float* src = (s0 < DSTATE) ? Bre : Bim;
  int sbase = (s0 < DSTATE) ? s0 : s0 - DSTATE;
  for (int rr = 0; rr < 32; rr += 8) {
    int s = sbase + r0 + rr;
    tile[r0 + rr][c] = src[(long)s * DIN + i0 + c] * (256.f * expf(ga[s]));
  }
  __syncthreads();
  for (int rr = 0; rr < 32; rr += 8) {
    int i = i0 + r0 + rr;
    float v = tile[c][r0 + rr];
    __half h = __float2half(v);
    __half l = __float2half(v - __half2float(h));
    Bh[(long)i * S2 + s0 + c] = h;
    Bl[(long)i * S2 + s0 + c] = l;
  }
}

// ---------------- y0[j] = 2*sum_s (cre*C_re[j,s] - cim*C_im[j,s]), state inline ----------------
__global__ void k_y0(const float* __restrict__ xr, const float* __restrict__ xi,
                     const float* __restrict__ nu, const float* __restrict__ th,
                     const float* __restrict__ Cre, const float* __restrict__ Cim,
                     float* __restrict__ y0) {
  int j = blockIdx.x;
  float acc = 0.f;
  for (int s = threadIdx.x; s < DSTATE; s += 256) {
    float lm = expf(-expf(nu[s]));
    float t = expf(th[s]);
    float lr = lm * cosf(t), li = lm * sinf(t);
    float cr = lr * xr[s] - li * xi[s];
    float ci = lr * xi[s] + li * xr[s];
    acc += cr * Cre[(long)j * DSTATE + s] - ci * Cim[(long)j * DSTATE + s];
  }
  for (int off = 32; off; off >>= 1) acc += __shfl_down(acc, off);
  __shared__ float red[4];
  if ((threadIdx.x & 63) == 0) red[threadIdx.x >> 6] = acc;
  __syncthreads();
  if (threadIdx.x == 0) y0[j] = 2.f * (red[0] + red[1] + red[2] + red[3]);
}

// ---------------- GEMM: out[M][N] = A[M][K] @ B^T[N][K] ----------------
// AMODE 1: A = 512*[Cre|-Cim] (dual source, hi-only RTN).  AMODE 2: A = u fp32 (hi-only RTN).
// EPI 0: plain store of fp32 partial at outF + z*M*N.  EPI 1: y = acc/256 + y0[col].
template <int BM, int BN, int AMODE, int EPI>
__global__ __launch_bounds__(256, 4) void k_gemm(
    const float* __restrict__ A, const float* __restrict__ A2,
    const __half* __restrict__ Bh, const __half* __restrict__ Bl,
    const float* __restrict__ extra, float* __restrict__ outF,
    int M, int N, int K, int kiters, int kchunk) {
  constexpr int FM = BM / 32;
  constexpr int FN = BN / 32;
  constexpr int ABYTES = BM * 64;
  constexpr int BBYTES = BN * 64;
  __shared__ alignas(16) char smem[ABYTES + 2 * BBYTES];
  char* sA = smem;
  char* sBh = smem + ABYTES;
  char* sBl = smem + ABYTES + BBYTES;

  const int tid = threadIdx.x;
  const int lane = tid & 63;
  const int wid = tid >> 6;
  const int wr = wid >> 1, wc = wid & 1;
  int bm0, bn0, kb;
  if constexpr (EPI == 1) {
    // XCD-aware swizzle: grid 1024 (divisible by 8 -> bijective).
    int wg = blockIdx.x;
    int lin = (wg & 7) * 128 + (wg >> 3);
    bm0 = (lin >> 3) * BM;
    bn0 = (lin & 7) * BN;
    kb = 0;
  } else {
    bm0 = blockIdx.y * BM;
    bn0 = blockIdx.x * BN;
    kb = blockIdx.z * kchunk;
  }
  const int r16 = lane & 15;
  const int ksl = lane >> 4;

  f32x4 acc[FM][FN];
#pragma unroll
  for (int i = 0; i < FM; ++i)
#pragma unroll
    for (int j = 0; j < FN; ++j) acc[i][j] = f32x4{0.f, 0.f, 0.f, 0.f};

  constexpr int APT = (BM * 8) / 256;  // f32x4 loads per thread for A tile
  constexpr int IPW = (BN / 16) / 4;   // global_load_lds insts per wave per buffer

  for (int kt = 0; kt < kiters; ++kt) {
    __syncthreads();
    // ---- stage A: fp32 -> f16 hi (RTN), swizzled ds_write ----
#pragma unroll
    for (int it = 0; it < APT; ++it) {
      int idx = it * 256 + tid;
      int row = idx >> 3;
      int k0 = (idx & 7) * 4;
      f32x4 v;
      if constexpr (AMODE == 2) {
        v = *(const f32x4*)(A + (long)(bm0 + row) * K + kb + kt * 32 + k0);
      } else {
        int s = kb + kt * 32 + k0;  // chunk never straddles DSTATE
        const float* src = (s < DSTATE) ? A : A2;
        int sc = (s < DSTATE) ? s : s - DSTATE;
        v = *(const f32x4*)(src + (long)(bm0 + row) * DSTATE + sc);
        v *= (s < DSTATE) ? 512.f : -512.f;  // 2*scale(256), sign folds the minus
      }
      union { __half h[4]; uint64_t u; } p;
#pragma unroll
      for (int j = 0; j < 4; ++j) p.h[j] = __float2half(v[j]);
      *(uint64_t*)(sA + lds_off(row, k0)) = p.u;
    }
    // ---- stage B via global_load_lds (linear dest, inverse-swizzled source) ----
#pragma unroll
    for (int ii = 0; ii < IPW; ++ii) {
      int inst = wid * IPW + ii;
      int row = inst * 16 + (lane >> 2);
      int slot = (lane & 3) ^ ((row >> 1) & 3);
      const __half* gh = Bh + (long)(bn0 + row) * K + kb + kt * 32 + slot * 8;
      const __half* gl = Bl + (long)(bn0 + row) * K + kb + kt * 32 + slot * 8;
      __builtin_amdgcn_global_load_lds((GLOBAL_AS const unsigned int*)gh,
                                       (LDS_AS unsigned int*)(sBh + inst * 1024), 16, 0, 0);
      __builtin_amdgcn_global_load_lds((GLOBAL_AS const unsigned int*)gl,
                                       (LDS_AS unsigned int*)(sBl + inst * 1024), 16, 0, 0);
    }
    __syncthreads();
    // ---- compute: 2-product (a * bh + a * bl) ----
    f16x8 a[FM], bh[FN], bl[FN];
#pragma unroll
    for (int m = 0; m < FM; ++m) {
      int row = wr * (BM / 2) + m * 16 + r16;
      a[m] = *(const f16x8*)(sA + lds_off(row, ksl * 8));
    }
#pragma unroll
    for (int n = 0; n < FN; ++n) {
      int row = wc * (BN / 2) + n * 16 + r16;
      bh[n] = *(const f16x8*)(sBh + lds_off(row, ksl * 8));
      bl[n] = *(const f16x8*)(sBl + lds_off(row, ksl * 8));
    }
#pragma unroll
    for (int m = 0; m < FM; ++m)
#pragma unroll
      for (int n = 0; n < FN; ++n)
        acc[m][n] = __builtin_amdgcn_mfma_f32_16x16x32_f16(a[m], bh[n], acc[m][n], 0, 0, 0);
#pragma unroll
    for (int m = 0; m < FM; ++m)
#pragma unroll
      for (int n = 0; n < FN; ++n)
        acc[m][n] = __builtin_amdgcn_mfma_f32_16x16x32_f16(a[m], bl[n], acc[m][n], 0, 0, 0);
  }

  // ---- epilogue (C/D layout: col = lane&15, row = (lane>>4)*4 + reg) ----
  const int rowb = (lane >> 4) * 4;
#pragma unroll
  for (int m = 0; m < FM; ++m)
#pragma unroll
    for (int n = 0; n < FN; ++n)
#pragma unroll
      for (int r = 0; r < 4; ++r) {
        int gr = bm0 + wr * (BM / 2) + m * 16 + rowb + r;
        int gc = bn0 + wc * (BN / 2) + n * 16 + r16;
        if constexpr (EPI == 0) {
          outF[(long)blockIdx.z * M * N + (long)gr * N + gc] = acc[m][n][r];
        } else {
          outF[(long)gr * N + gc] = acc[m][n][r] * (1.f / 256.f) + extra[gc];
        }
      }
}

// ---------------- M = sum(partials)/65536 + D -> store 256*M hi/lo ----------------
// Partials hold 65536*(M - D) summed over nparts; v = sum/256 + 256*D = 256*M.
__global__ void k_redM(const float* __restrict__ P, const float* __restrict__ D,
                       __half* __restrict__ Mh, __half* __restrict__ Ml, int nparts) {
  int idx = (blockIdx.x * 256 + threadIdx.x) * 4;
  f32x4 s = {0.f, 0.f, 0.f, 0.f};
  for (int p = 0; p < nparts; ++p)
    s += *(const f32x4*)(P + ((long)p << 20) + idx);
  f32x4 d = *(const f32x4*)(D + idx);
  union { __half h[4]; uint64_t u; } ph, pl;
#pragma unroll
  for (int j = 0; j < 4; ++j) {
    float v = s[j] * (1.f / 256.f) + 256.f * d[j];
    __half hh = __float2half(v);
    ph.h[j] = hh;
    pl.h[j] = __float2half(v - __half2float(hh));
  }
  *(uint64_t*)(Mh + idx) = ph.u;
  *(uint64_t*)(Ml + idx) = pl.u;
}

extern "C" void kernel_launch(void* const* d_in, const int* in_sizes, int n_in,
                              void* d_out, int out_size, void* d_ws, size_t ws_size,
                              hipStream_t stream) {
  const float* u   = (const float*)d_in[0];
  const float* xr  = (const float*)d_in[1];
  const float* xi  = (const float*)d_in[2];
  const float* nu  = (const float*)d_in[3];
  const float* th  = (const float*)d_in[4];
  const float* ga  = (const float*)d_in[5];
  const float* Bre = (const float*)d_in[6];
  const float* Bim = (const float*)d_in[7];
  const float* Cre = (const float*)d_in[8];
  const float* Cim = (const float*)d_in[9];
  const float* Dm  = (const float*)d_in[10];
  float* y = (float*)d_out;

  char* w = (char*)d_ws;
  float* y0  = (float*)(w);                                  // 4 KB
  __half* Bgh = (__half*)(w + 65536);                        // [DIN][S2] 8 MB
  __half* Bgl = (__half*)(w + 65536 + 8388608);              // 8 MB
  __half* Mh  = (__half*)(w + 65536 + 16777216);             // 2 MB
  __half* Ml  = (__half*)(w + 65536 + 16777216 + 2097152);   // 2 MB
  const size_t pbase = 65536 + 16777216 + 4194304;
  float* Mpart = (float*)(w + pbase);                        // KS * 4 MB

  // Split-K factor chosen by available workspace (deterministic across calls).
  const size_t part = (size_t)DOUT * DIN * 4;
  int KS = (ws_size >= pbase + 8 * part) ? 8 : (ws_size >= pbase + 4 * part) ? 4 : 2;

  k_bgt<<<dim3(S2 / 32, DIN / 32), 256, 0, stream>>>(Bre, Bim, ga, Bgh, Bgl);
  k_y0<<<DOUT, 256, 0, stream>>>(xr, xi, nu, th, Cre, Cim, y0);
  // M-build: 128^2 tile, split-K x KS, plain fp32 partial stores
  k_gemm<128, 128, 1, 0><<<dim3(DIN / 128, DOUT / 128, KS), 256, 0, stream>>>(
      Cre, Cim, Bgh, Bgl, nullptr, Mpart, DOUT, DIN, S2, (S2 / KS) / 32, S2 / KS);
  k_redM<<<1024, 256, 0, stream>>>(Mpart, Dm, Mh, Ml, KS);
  // main: y[b][j] = (sum_i u_hi[b][i] * 256M[j][i])/256 + y0[j]
  k_gemm<128, 128, 2, 1><<<(BATCH / 128) * (DOUT / 128), 256, 0, stream>>>(
      u, nullptr, Mh, Ml, y0, y, BATCH, DOUT, DIN, DIN / 32, 0);
}

// Round 12
// 291.426 us; speedup vs baseline: 1.0179x; 1.0179x over previous
//
#include <hip/hip_runtime.h>
#include <hip/hip_fp16.h>
#include <stdint.h>

// LRU single-step collapsed:  y = u @ M^T + y0
//   M  = 2*(C_re G B_re - C_im G B_im) + D,  y0 = 2*(C_re c_re - C_im c_im), c = lam*x
// f16 MFMA, scaled hi/lo splits (x256 keeps lo-parts f16-normal).
// Prep: u->f16 (k_uh), Bg transpose+split (k_bgt), y0 (k_y0),
//       M-build split-K fp32 partials (k_mbuild) + reduce/split (k_redM).
// Main (k_main): 128^2, ALL operands staged via global_load_lds (A=u_h f16, B=Mh/Ml).

typedef _Float16 f16x8 __attribute__((ext_vector_type(8)));
typedef float f32x4 __attribute__((ext_vector_type(4)));

#define GLOBAL_AS __attribute__((address_space(1)))
#define LDS_AS __attribute__((address_space(3)))

constexpr int BATCH = 16384, DIN = 1024, DSTATE = 2048, DOUT = 1024;
constexpr int S2 = 2 * DSTATE;  // 4096

// Rows are 32 f16 = 64B = 4 x 16B slots; XOR-swizzle slot by ((row>>1)&3).
// Verified: SQ_LDS_BANK_CONFLICT == 0 (R1/R3/R6/R9).
__device__ __forceinline__ int lds_off(int row, int k) {
  int slot = k >> 3;
  int sl = slot ^ ((row >> 1) & 3);
  return row * 64 + sl * 16 + (k & 7) * 2;
}

// ---------------- u_h = f16(u), RTN ----------------
__global__ void k_uh(const float* __restrict__ u, __half* __restrict__ uh) {
  long i = ((long)blockIdx.x * 256 + threadIdx.x) * 8;
  f32x4 a = *(const f32x4*)(u + i);
  f32x4 b = *(const f32x4*)(u + i + 4);
  union { __half h[8]; uint4 v; } p;
#pragma unroll
  for (int j = 0; j < 4; ++j) {
    p.h[j] = __float2half(a[j]);
    p.h[4 + j] = __float2half(b[j]);
  }
  *(uint4*)(uh + i) = p.v;
}

// ---------------- Bgt[i][s2] = 256*exp(ga[s])*B[s][i], transposed, f16 hi/lo ----------------
__global__ void k_bgt(const float* __restrict__ Bre, const float* __restrict__ Bim,
                      const float* __restrict__ ga, __half* __restrict__ Bh,
                      __half* __restrict__ Bl) {
  __shared__ float tile[32][33];
  int s0 = blockIdx.x * 32, i0 = blockIdx.y * 32;
  int c = threadIdx.x & 31, r0 = threadIdx.x >> 5;  // 8 rows per pass
  const float* src = (s0 < DSTATE) ? Bre : Bim;
  int sbase = (s0 < DSTATE) ? s0 : s0 - DSTATE;
  for (int rr = 0; rr < 32; rr += 8) {
    int s = sbase + r0 + rr;
    tile[r0 + rr][c] = src[(long)s * DIN + i0 + c] * (256.f * expf(ga[s]));
  }
  __syncthreads();
  for (int rr = 0; rr < 32; rr += 8) {
    int i = i0 + r0 + rr;
    float v = tile[c][r0 + rr];
    __half h = __float2half(v);
    __half l = __float2half(v - __half2float(h));
    Bh[(long)i * S2 + s0 + c] = h;
    Bl[(long)i * S2 + s0 + c] = l;
  }
}

// ---------------- y0[j] = 2*sum_s (cre*C_re[j,s] - cim*C_im[j,s]), state inline ----------------
__global__ void k_y0(const float* __restrict__ xr, const float* __restrict__ xi,
                     const float* __restrict__ nu, const float* __restrict__ th,
                     const float* __restrict__ Cre, const float* __restrict__ Cim,
                     float* __restrict__ y0) {
  int j = blockIdx.x;
  float acc = 0.f;
  for (int s = threadIdx.x; s < DSTATE; s += 256) {
    float lm = expf(-expf(nu[s]));
    float t = expf(th[s]);
    float lr = lm * cosf(t), li = lm * sinf(t);
    float cr = lr * xr[s] - li * xi[s];
    float ci = lr * xi[s] + li * xr[s];
    acc += cr * Cre[(long)j * DSTATE + s] - ci * Cim[(long)j * DSTATE + s];
  }
  for (int off = 32; off; off >>= 1) acc += __shfl_down(acc, off);
  __shared__ float red[4];
  if ((threadIdx.x & 63) == 0) red[threadIdx.x >> 6] = acc;
  __syncthreads();
  if (threadIdx.x == 0) y0[j] = 2.f * (red[0] + red[1] + red[2] + red[3]);
}

// ---------------- M-build: Mpart[z] = 512*[Cre|-Cim]_hi @ (Bh+Bl)^T over K-chunk ----------------
__global__ __launch_bounds__(256, 2) void k_mbuild(
    const float* __restrict__ Cre, const float* __restrict__ Cim,
    const __half* __restrict__ Bh, const __half* __restrict__ Bl,
    float* __restrict__ outF, int kiters, int kchunk) {
  __shared__ alignas(16) char smem[8192 + 2 * 8192];
  char* sA = smem;
  char* sBh = smem + 8192;
  char* sBl = smem + 16384;

  const int tid = threadIdx.x;
  const int lane = tid & 63;
  const int wid = tid >> 6;
  const int wr = wid >> 1, wc = wid & 1;
  const int bm0 = blockIdx.y * 128;
  const int bn0 = blockIdx.x * 128;
  const int kb = blockIdx.z * kchunk;
  const int r16 = lane & 15;
  const int ksl = lane >> 4;

  f32x4 acc[4][4];
#pragma unroll
  for (int i = 0; i < 4; ++i)
#pragma unroll
    for (int j = 0; j < 4; ++j) acc[i][j] = f32x4{0.f, 0.f, 0.f, 0.f};

  for (int kt = 0; kt < kiters; ++kt) {
    __syncthreads();
    // stage A: fp32 C -> f16 hi (RTN), swizzled ds_write
#pragma unroll
    for (int it = 0; it < 4; ++it) {
      int idx = it * 256 + tid;
      int row = idx >> 3;
      int k0 = (idx & 7) * 4;
      int s = kb + kt * 32 + k0;  // chunk never straddles DSTATE
      const float* src = (s < DSTATE) ? Cre : Cim;
      int sc = (s < DSTATE) ? s : s - DSTATE;
      f32x4 v = *(const f32x4*)(src + (long)(bm0 + row) * DSTATE + sc);
      v *= (s < DSTATE) ? 512.f : -512.f;  // 2*scale(256), sign folds the minus
      union { __half h[4]; uint64_t u; } p;
#pragma unroll
      for (int j = 0; j < 4; ++j) p.h[j] = __float2half(v[j]);
      *(uint64_t*)(sA + lds_off(row, k0)) = p.u;
    }
    // stage B via global_load_lds (linear dest, inverse-swizzled source)
#pragma unroll
    for (int ii = 0; ii < 2; ++ii) {
      int inst = wid * 2 + ii;
      int row = inst * 16 + (lane >> 2);
      int slot = (lane & 3) ^ ((row >> 1) & 3);
      const __half* gh = Bh + (long)(bn0 + row) * S2 + kb + kt * 32 + slot * 8;
      const __half* gl = Bl + (long)(bn0 + row) * S2 + kb + kt * 32 + slot * 8;
      __builtin_amdgcn_global_load_lds((GLOBAL_AS const unsigned int*)gh,
                                       (LDS_AS unsigned int*)(sBh + inst * 1024), 16, 0, 0);
      __builtin_amdgcn_global_load_lds((GLOBAL_AS const unsigned int*)gl,
                                       (LDS_AS unsigned int*)(sBl + inst * 1024), 16, 0, 0);
    }
    __syncthreads();
    f16x8 a[4], bh[4], bl[4];
#pragma unroll
    for (int m = 0; m < 4; ++m)
      a[m] = *(const f16x8*)(sA + lds_off(wr * 64 + m * 16 + r16, ksl * 8));
#pragma unroll
    for (int n = 0; n < 4; ++n) {
      bh[n] = *(const f16x8*)(sBh + lds_off(wc * 64 + n * 16 + r16, ksl * 8));
      bl[n] = *(const f16x8*)(sBl + lds_off(wc * 64 + n * 16 + r16, ksl * 8));
    }
#pragma unroll
    for (int m = 0; m < 4; ++m)
#pragma unroll
      for (int n = 0; n < 4; ++n)
        acc[m][n] = __builtin_amdgcn_mfma_f32_16x16x32_f16(a[m], bh[n], acc[m][n], 0, 0, 0);
#pragma unroll
    for (int m = 0; m < 4; ++m)
#pragma unroll
      for (int n = 0; n < 4; ++n)
        acc[m][n] = __builtin_amdgcn_mfma_f32_16x16x32_f16(a[m], bl[n], acc[m][n], 0, 0, 0);
  }

  const int rowb = (lane >> 4) * 4;
#pragma unroll
  for (int m = 0; m < 4; ++m)
#pragma unroll
    for (int n = 0; n < 4; ++n)
#pragma unroll
      for (int r = 0; r < 4; ++r) {
        int gr = bm0 + wr * 64 + m * 16 + rowb + r;
        int gc = bn0 + wc * 64 + n * 16 + r16;
        outF[(long)blockIdx.z * DOUT * DIN + (long)gr * DIN + gc] = acc[m][n][r];
      }
}

// ---------------- M = sum(partials)/65536 + D -> store 256*M hi/lo ----------------
__global__ void k_redM(const float* __restrict__ P, const float* __restrict__ D,
                       __half* __restrict__ Mh, __half* __restrict__ Ml, int nparts) {
  int idx = (blockIdx.x * 256 + threadIdx.x) * 4;
  f32x4 s = {0.f, 0.f, 0.f, 0.f};
  for (int p = 0; p < nparts; ++p)
    s += *(const f32x4*)(P + ((long)p << 20) + idx);
  f32x4 d = *(const f32x4*)(D + idx);
  union { __half h[4]; uint64_t u; } ph, pl;
#pragma unroll
  for (int j = 0; j < 4; ++j) {
    float v = s[j] * (1.f / 256.f) + 256.f * d[j];  // = 256 * M[j]
    __half hh = __float2half(v);
    ph.h[j] = hh;
    pl.h[j] = __float2half(v - __half2float(hh));
  }
  *(uint64_t*)(Mh + idx) = ph.u;
  *(uint64_t*)(Ml + idx) = pl.u;
}

// ---------------- main: y[b][j] = (u_h @ (256M)^T)/256 + y0[j] ----------------
// TEMPLATE UH: 1 = A from u_h f16 via global_load_lds; 0 = A from u fp32 (reg-staged).
template <int UH>
__global__ __launch_bounds__(256, 2) void k_main(
    const __half* __restrict__ Ah, const float* __restrict__ Af,
    const __half* __restrict__ Bh, const __half* __restrict__ Bl,
    const float* __restrict__ y0, float* __restrict__ out) {
  constexpr int K = DIN, N = DOUT;
  __shared__ alignas(16) char smem[8192 + 2 * 8192];
  char* sA = smem;
  char* sBh = smem + 8192;
  char* sBl = smem + 16384;

  const int tid = threadIdx.x;
  const int lane = tid & 63;
  const int wid = tid >> 6;
  const int wr = wid >> 1, wc = wid & 1;
  // XCD-aware swizzle: grid 1024 (divisible by 8 -> bijective).
  const int wg = blockIdx.x;
  const int lin = (wg & 7) * 128 + (wg >> 3);
  const int bm0 = (lin >> 3) * 128;
  const int bn0 = (lin & 7) * 128;
  const int r16 = lane & 15;
  const int ksl = lane >> 4;

  f32x4 acc[4][4];
#pragma unroll
  for (int i = 0; i < 4; ++i)
#pragma unroll
    for (int j = 0; j < 4; ++j) acc[i][j] = f32x4{0.f, 0.f, 0.f, 0.f};

  for (int kt = 0; kt < K / 32; ++kt) {
    __syncthreads();
    if constexpr (UH == 0) {
      // A: fp32 u -> f16 RTN, swizzled ds_write
#pragma unroll
      for (int it = 0; it < 4; ++it) {
        int idx = it * 256 + tid;
        int row = idx >> 3;
        int k0 = (idx & 7) * 4;
        f32x4 v = *(const f32x4*)(Af + (long)(bm0 + row) * K + kt * 32 + k0);
        union { __half h[4]; uint64_t u; } p;
#pragma unroll
        for (int j = 0; j < 4; ++j) p.h[j] = __float2half(v[j]);
        *(uint64_t*)(sA + lds_off(row, k0)) = p.u;
      }
    }
    // gl_lds staging (A f16 when UH==1, plus Bh/Bl)
#pragma unroll
    for (int ii = 0; ii < 2; ++ii) {
      int inst = wid * 2 + ii;
      int row = inst * 16 + (lane >> 2);
      int slot = (lane & 3) ^ ((row >> 1) & 3);
      if constexpr (UH == 1) {
        const __half* ga = Ah + (long)(bm0 + row) * K + kt * 32 + slot * 8;
        __builtin_amdgcn_global_load_lds((GLOBAL_AS const unsigned int*)ga,
                                         (LDS_AS unsigned int*)(sA + inst * 1024), 16, 0, 0);
      }
      const __half* gh = Bh + (long)(bn0 + row) * K + kt * 32 + slot * 8;
      const __half* gl = Bl + (long)(bn0 + row) * K + kt * 32 + slot * 8;
      __builtin_amdgcn_global_load_lds((GLOBAL_AS const unsigned int*)gh,
                                       (LDS_AS unsigned int*)(sBh + inst * 1024), 16, 0, 0);
      __builtin_amdgcn_global_load_lds((GLOBAL_AS const unsigned int*)gl,
                                       (LDS_AS unsigned int*)(sBl + inst * 1024), 16, 0, 0);
    }
    __syncthreads();
    f16x8 a[4], bh[4], bl[4];
#pragma unroll
    for (int m = 0; m < 4; ++m)
      a[m] = *(const f16x8*)(sA + lds_off(wr * 64 + m * 16 + r16, ksl * 8));
#pragma unroll
    for (int n = 0; n < 4; ++n) {
      bh[n] = *(const f16x8*)(sBh + lds_off(wc * 64 + n * 16 + r16, ksl * 8));
      bl[n] = *(const f16x8*)(sBl + lds_off(wc * 64 + n * 16 + r16, ksl * 8));
    }
#pragma unroll
    for (int m = 0; m < 4; ++m)
#pragma unroll
      for (int n = 0; n < 4; ++n)
        acc[m][n] = __builtin_amdgcn_mfma_f32_16x16x32_f16(a[m], bh[n], acc[m][n], 0, 0, 0);
#pragma unroll
    for (int m = 0; m < 4; ++m)
#pragma unroll
      for (int n = 0; n < 4; ++n)
        acc[m][n] = __builtin_amdgcn_mfma_f32_16x16x32_f16(a[m], bl[n], acc[m][n], 0, 0, 0);
  }

  const int rowb = (lane >> 4) * 4;
#pragma unroll
  for (int m = 0; m < 4; ++m)
#pragma unroll
    for (int n = 0; n < 4; ++n)
#pragma unroll
      for (int r = 0; r < 4; ++r) {
        int gr = bm0 + wr * 64 + m * 16 + rowb + r;
        int gc = bn0 + wc * 64 + n * 16 + r16;
        out[(long)gr * N + gc] = acc[m][n][r] * (1.f / 256.f) + y0[gc];
      }
}

extern "C" void kernel_launch(void* const* d_in, const int* in_sizes, int n_in,
                              void* d_out, int out_size, void* d_ws, size_t ws_size,
                              hipStream_t stream) {
  const float* u   = (const float*)d_in[0];
  const float* xr  = (const float*)d_in[1];
  const float* xi  = (const float*)d_in[2];
  const float* nu  = (const float*)d_in[3];
  const float* th  = (const float*)d_in[4];
  const float* ga  = (const float*)d_in[5];
  const float* Bre = (const float*)d_in[6];
  const float* Bim = (const float*)d_in[7];
  const float* Cre = (const float*)d_in[8];
  const float* Cim = (const float*)d_in[9];
  const float* Dm  = (const float*)d_in[10];
  float* y = (float*)d_out;

  char* w = (char*)d_ws;
  float* y0  = (float*)(w);                                  // 64 KB slot
  __half* Bgh = (__half*)(w + 65536);                        // [DIN][S2] 8 MB
  __half* Bgl = (__half*)(w + 65536 + 8388608);              // 8 MB
  __half* Mh  = (__half*)(w + 65536 + 16777216);             // 2 MB
  __half* Ml  = (__half*)(w + 65536 + 16777216 + 2097152);   // 2 MB
  const size_t base = 65536 + 16777216 + 4194304;            // 21.04 MB
  __half* u_h = (__half*)(w + base);                         // 32 MB (if used)
  const size_t part = (size_t)DOUT * DIN * 4;                // 4 MB

  // Deterministic layout selection from ws_size (graph-safe).
  const size_t uh_bytes = (size_t)BATCH * DIN * 2;
  bool use_uh = ws_size >= base + uh_bytes + 2 * part;
  float* Mpart = (float*)(use_uh ? (w + base + uh_bytes) : (w + base));
  size_t avail = ws_size - (use_uh ? base + uh_bytes : base);
  int KS = (avail >= 8 * part) ? 8 : (avail >= 4 * part) ? 4 : 2;

  if (use_uh) k_uh<<<BATCH * DIN / (256 * 8), 256, 0, stream>>>(u, u_h);
  k_bgt<<<dim3(S2 / 32, DIN / 32), 256, 0, stream>>>(Bre, Bim, ga, Bgh, Bgl);
  k_y0<<<DOUT, 256, 0, stream>>>(xr, xi, nu, th, Cre, Cim, y0);
  k_mbuild<<<dim3(DIN / 128, DOUT / 128, KS), 256, 0, stream>>>(
      Cre, Cim, Bgh, Bgl, Mpart, (S2 / KS) / 32, S2 / KS);
  k_redM<<<1024, 256, 0, stream>>>(Mpart, Dm, Mh, Ml, KS);
  if (use_uh)
    k_main<1><<<(BATCH / 128) * (DOUT / 128), 256, 0, stream>>>(u_h, nullptr, Mh, Ml, y0, y);
  else
    k_main<0><<<(BATCH / 128) * (DOUT / 128), 256, 0, stream>>>(nullptr, u, Mh, Ml, y0, y);
}

// Round 14
// 282.377 us; speedup vs baseline: 1.0506x; 1.0320x over previous
//
#include <hip/hip_runtime.h>
#include <hip/hip_fp16.h>
#include <stdint.h>

// LRU single-step collapsed:  y = u @ M^T + y0
//   M  = 2*(C_re G B_re - C_im G B_im) + D,  y0 = 2*(C_re c_re - C_im c_im), c = lam*x
// f16 MFMA, scaled hi/lo splits (x256 keeps lo-parts f16-normal).
// Unified 2-phase double-buffered GEMM template (1 barrier per K-step):
//   k_mbuild: A = 512*[Cre|-Cim] fp32->f16-hi, split-K, fp32 partial stores.
//   k_main:   A = u fp32->f16-hi, epilogue y = acc/256 + y0.

typedef _Float16 f16x8 __attribute__((ext_vector_type(8)));
typedef float f32x4 __attribute__((ext_vector_type(4)));

#define GLOBAL_AS __attribute__((address_space(1)))
#define LDS_AS __attribute__((address_space(3)))

constexpr int BATCH = 16384, DIN = 1024, DSTATE = 2048, DOUT = 1024;
constexpr int S2 = 2 * DSTATE;  // 4096

// Rows are 32 f16 = 64B = 4 x 16B slots; XOR-swizzle slot by ((row>>1)&3).
// Verified: SQ_LDS_BANK_CONFLICT == 0 (R1/R3/R6/R9/R12).
__device__ __forceinline__ int lds_off(int row, int k) {
  int slot = k >> 3;
  int sl = slot ^ ((row >> 1) & 3);
  return row * 64 + sl * 16 + (k & 7) * 2;
}

// ---------------- Bgt[i][s2] = 256*exp(ga[s])*B[s][i], transposed, f16 hi/lo ----------------
__global__ void k_bgt(const float* __restrict__ Bre, const float* __restrict__ Bim,
                      const float* __restrict__ ga, __half* __restrict__ Bh,
                      __half* __restrict__ Bl) {
  __shared__ float tile[32][33];
  int s0 = blockIdx.x * 32, i0 = blockIdx.y * 32;
  int c = threadIdx.x & 31, r0 = threadIdx.x >> 5;  // 8 rows per pass
  const float* src = (s0 < DSTATE) ? Bre : Bim;
  int sbase = (s0 < DSTATE) ? s0 : s0 - DSTATE;
  for (int rr = 0; rr < 32; rr += 8) {
    int s = sbase + r0 + rr;
    tile[r0 + rr][c] = src[(long)s * DIN + i0 + c] * (256.f * expf(ga[s]));
  }
  __syncthreads();
  for (int rr = 0; rr < 32; rr += 8) {
    int i = i0 + r0 + rr;
    float v = tile[c][r0 + rr];
    __half h = __float2half(v);
    __half l = __float2half(v - __half2float(h));
    Bh[(long)i * S2 + s0 + c] = h;
    Bl[(long)i * S2 + s0 + c] = l;
  }
}

// ---------------- y0[j] = 2*sum_s (cre*C_re[j,s] - cim*C_im[j,s]), state inline ----------------
__global__ void k_y0(const float* __restrict__ xr, const float* __restrict__ xi,
                     const float* __restrict__ nu, const float* __restrict__ th,
                     const float* __restrict__ Cre, const float* __restrict__ Cim,
                     float* __restrict__ y0) {
  int j = blockIdx.x;
  float acc = 0.f;
  for (int s = threadIdx.x; s < DSTATE; s += 256) {
    float lm = expf(-expf(nu[s]));
    float t = expf(th[s]);
    float lr = lm * cosf(t), li = lm * sinf(t);
    float cr = lr * xr[s] - li * xi[s];
    float ci = lr * xi[s] + li * xr[s];
    acc += cr * Cre[(long)j * DSTATE + s] - ci * Cim[(long)j * DSTATE + s];
  }
  for (int off = 32; off; off >>= 1) acc += __shfl_down(acc, off);
  __shared__ float red[4];
  if ((threadIdx.x & 63) == 0) red[threadIdx.x >> 6] = acc;
  __syncthreads();
  if (threadIdx.x == 0) y0[j] = 2.f * (red[0] + red[1] + red[2] + red[3]);
}

// ---------------- staging helpers ----------------
template <int AMODE>
__device__ __forceinline__ f32x4 load_a(const float* __restrict__ A,
                                        const float* __restrict__ A2,
                                        int bm0, int K, int kglob, int tid, int it) {
  int idx = it * 256 + tid;
  int row = idx >> 3;
  int k0 = (idx & 7) * 4;
  if constexpr (AMODE == 2) {
    return *(const f32x4*)(A + (long)(bm0 + row) * K + kglob + k0);
  } else {
    int s = kglob + k0;  // split-K chunk never straddles DSTATE
    const float* src = (s < DSTATE) ? A : A2;
    int sc = (s < DSTATE) ? s : s - DSTATE;
    f32x4 v = *(const f32x4*)(src + (long)(bm0 + row) * DSTATE + sc);
    return v * ((s < DSTATE) ? 512.f : -512.f);  // 2*scale(256), sign folds minus
  }
}

__device__ __forceinline__ void write_a(f32x4 v, char* sA, int tid, int it) {
  int idx = it * 256 + tid;
  int row = idx >> 3;
  int k0 = (idx & 7) * 4;
  union { __half h[4]; uint64_t u; } p;
#pragma unroll
  for (int j = 0; j < 4; ++j) p.h[j] = __float2half(v[j]);
  *(uint64_t*)(sA + lds_off(row, k0)) = p.u;
}

__device__ __forceinline__ void stage_b(const __half* __restrict__ Bh,
                                        const __half* __restrict__ Bl,
                                        char* sBh, char* sBl,
                                        int bn0, int K, int kglob, int wid, int lane) {
#pragma unroll
  for (int ii = 0; ii < 2; ++ii) {
    int inst = wid * 2 + ii;
    int row = inst * 16 + (lane >> 2);
    int slot = (lane & 3) ^ ((row >> 1) & 3);  // inverse of read swizzle
    const __half* gh = Bh + (long)(bn0 + row) * K + kglob + slot * 8;
    const __half* gl = Bl + (long)(bn0 + row) * K + kglob + slot * 8;
    __builtin_amdgcn_global_load_lds((GLOBAL_AS const unsigned int*)gh,
                                     (LDS_AS unsigned int*)(sBh + inst * 1024), 16, 0, 0);
    __builtin_amdgcn_global_load_lds((GLOBAL_AS const unsigned int*)gl,
                                     (LDS_AS unsigned int*)(sBl + inst * 1024), 16, 0, 0);
  }
}

// ---------------- unified 2-phase dbuf GEMM: out = A[M][K] @ B^T[N][K] ----------------
// AMODE 1: A = 512*[Cre|-Cim] fp32 (dual source).  AMODE 2: A = u fp32.
// EPI 0: fp32 partial store at outF + z*M*N.        EPI 1: y = acc/256 + y0[col].
// LDS: 2 buffers x (A 8K | Bh 8K | Bl 8K) = 48 KB. One __syncthreads per K-step
// (its implicit vmcnt(0)+lgkmcnt(0) drain makes the handoff safe).
template <int AMODE, int EPI>
__global__ __launch_bounds__(256, 2) void k_gemm2(
    const float* __restrict__ A, const float* __restrict__ A2,
    const __half* __restrict__ Bh, const __half* __restrict__ Bl,
    const float* __restrict__ extra, float* __restrict__ outF,
    int K, int N, int kiters, int kchunk) {
  __shared__ alignas(16) char smem[2 * 24576];

  const int tid = threadIdx.x;
  const int lane = tid & 63;
  const int wid = tid >> 6;
  const int wr = wid >> 1, wc = wid & 1;
  int bm0, bn0, kb;
  if constexpr (EPI == 1) {
    // XCD-aware swizzle: grid 1024 (divisible by 8 -> bijective).
    int wg = blockIdx.x;
    int lin = (wg & 7) * 128 + (wg >> 3);
    bm0 = (lin >> 3) * 128;
    bn0 = (lin & 7) * 128;
    kb = 0;
  } else {
    bm0 = blockIdx.y * 128;
    bn0 = blockIdx.x * 128;
    kb = blockIdx.z * kchunk;
  }
  const int r16 = lane & 15;
  const int ksl = lane >> 4;

  f32x4 acc[4][4];
#pragma unroll
  for (int i = 0; i < 4; ++i)
#pragma unroll
    for (int j = 0; j < 4; ++j) acc[i][j] = f32x4{0.f, 0.f, 0.f, 0.f};

  // ---- prologue: stage K-step 0 into buffer 0 ----
  f32x4 va[4];
#pragma unroll
  for (int it = 0; it < 4; ++it) va[it] = load_a<AMODE>(A, A2, bm0, K, kb, tid, it);
  stage_b(Bh, Bl, smem + 8192, smem + 16384, bn0, K, kb, wid, lane);
#pragma unroll
  for (int it = 0; it < 4; ++it) write_a(va[it], smem, tid, it);
  __syncthreads();  // drains vmcnt(0)+lgkmcnt(0): buffer 0 ready

  for (int kt = 0; kt < kiters; ++kt) {
    char* cur = smem + (kt & 1) * 24576;
    char* nxt = smem + ((kt + 1) & 1) * 24576;
    const bool more = (kt + 1 < kiters);
    // ---- issue next-step loads first (latency hides under MFMAs) ----
    if (more) {
      int kg = kb + (kt + 1) * 32;
#pragma unroll
      for (int it = 0; it < 4; ++it) va[it] = load_a<AMODE>(A, A2, bm0, K, kg, tid, it);
      stage_b(Bh, Bl, nxt + 8192, nxt + 16384, bn0, K, kg, wid, lane);
    }
    // ---- compute current buffer: 2-product (a*bh + a*bl) ----
    f16x8 a[4], bh[4], bl[4];
#pragma unroll
    for (int m = 0; m < 4; ++m)
      a[m] = *(const f16x8*)(cur + lds_off(wr * 64 + m * 16 + r16, ksl * 8));
#pragma unroll
    for (int n = 0; n < 4; ++n) {
      bh[n] = *(const f16x8*)(cur + 8192 + lds_off(wc * 64 + n * 16 + r16, ksl * 8));
      bl[n] = *(const f16x8*)(cur + 16384 + lds_off(wc * 64 + n * 16 + r16, ksl * 8));
    }
#pragma unroll
    for (int m = 0; m < 4; ++m)
#pragma unroll
      for (int n = 0; n < 4; ++n)
        acc[m][n] = __builtin_amdgcn_mfma_f32_16x16x32_f16(a[m], bh[n], acc[m][n], 0, 0, 0);
#pragma unroll
    for (int m = 0; m < 4; ++m)
#pragma unroll
      for (int n = 0; n < 4; ++n)
        acc[m][n] = __builtin_amdgcn_mfma_f32_16x16x32_f16(a[m], bl[n], acc[m][n], 0, 0, 0);
    // ---- write next A tile (cvt overlaps tail of MFMAs), then handoff ----
    if (more) {
#pragma unroll
      for (int it = 0; it < 4; ++it) write_a(va[it], nxt, tid, it);
    }
    __syncthreads();  // implicit vmcnt(0)+lgkmcnt(0): next buffer ready
  }

  // ---- epilogue (C/D layout: col = lane&15, row = (lane>>4)*4 + reg) ----
  const int rowb = (lane >> 4) * 4;
#pragma unroll
  for (int m = 0; m < 4; ++m)
#pragma unroll
    for (int n = 0; n < 4; ++n)
#pragma unroll
      for (int r = 0; r < 4; ++r) {
        int gr = bm0 + wr * 64 + m * 16 + rowb + r;
        int gc = bn0 + wc * 64 + n * 16 + r16;
        if constexpr (EPI == 0) {
          outF[(long)blockIdx.z * DOUT * DIN + (long)gr * N + gc] = acc[m][n][r];
        } else {
          outF[(long)gr * N + gc] = acc[m][n][r] * (1.f / 256.f) + extra[gc];
        }
      }
}

// ---------------- M = sum(partials)/65536 + D -> store 256*M hi/lo ----------------
__global__ void k_redM(const float* __restrict__ P, const float* __restrict__ D,
                       __half* __restrict__ Mh, __half* __restrict__ Ml, int nparts) {
  int idx = (blockIdx.x * 256 + threadIdx.x) * 4;
  f32x4 s = {0.f, 0.f, 0.f, 0.f};
  for (int p = 0; p < nparts; ++p)
    s += *(const f32x4*)(P + ((long)p << 20) + idx);
  f32x4 d = *(const f32x4*)(D + idx);
  union { __half h[4]; uint64_t u; } ph, pl;
#pragma unroll
  for (int j = 0; j < 4; ++j) {
    float v = s[j] * (1.f / 256.f) + 256.f * d[j];  // = 256 * M[j]
    __half hh = __float2half(v);
    ph.h[j] = hh;
    pl.h[j] = __float2half(v - __half2float(hh));
  }
  *(uint64_t*)(Mh + idx) = ph.u;
  *(uint64_t*)(Ml + idx) = pl.u;
}

extern "C" void kernel_launch(void* const* d_in, const int* in_sizes, int n_in,
                              void* d_out, int out_size, void* d_ws, size_t ws_size,
                              hipStream_t stream) {
  const float* u   = (const float*)d_in[0];
  const float* xr  = (const float*)d_in[1];
  const float* xi  = (const float*)d_in[2];
  const float* nu  = (const float*)d_in[3];
  const float* th  = (const float*)d_in[4];
  const float* ga  = (const float*)d_in[5];
  const float* Bre = (const float*)d_in[6];
  const float* Bim = (const float*)d_in[7];
  const float* Cre = (const float*)d_in[8];
  const float* Cim = (const float*)d_in[9];
  const float* Dm  = (const float*)d_in[10];
  float* y = (float*)d_out;

  char* w = (char*)d_ws;
  float* y0  = (float*)(w);                                  // 64 KB slot
  __half* Bgh = (__half*)(w + 65536);                        // [DIN][S2] 8 MB
  __half* Bgl = (__half*)(w + 65536 + 8388608);              // 8 MB
  __half* Mh  = (__half*)(w + 65536 + 16777216);             // 2 MB
  __half* Ml  = (__half*)(w + 65536 + 16777216 + 2097152);   // 2 MB
  const size_t base = 65536 + 16777216 + 4194304;            // ~21 MB
  float* Mpart = (float*)(w + base);                         // KS * 4 MB
  const size_t part = (size_t)DOUT * DIN * 4;

  // Split-K factor chosen by available workspace (deterministic, graph-safe).
  int KS = (ws_size >= base + 8 * part) ? 8 : (ws_size >= base + 4 * part) ? 4 : 2;

  k_bgt<<<dim3(S2 / 32, DIN / 32), 256, 0, stream>>>(Bre, Bim, ga, Bgh, Bgl);
  k_y0<<<DOUT, 256, 0, stream>>>(xr, xi, nu, th, Cre, Cim, y0);
  // M-build: 128^2 tile, split-K x KS, 2-phase dbuf, plain fp32 partial stores
  k_gemm2<1, 0><<<dim3(DIN / 128, DOUT / 128, KS), 256, 0, stream>>>(
      Cre, Cim, Bgh, Bgl, nullptr, Mpart, S2, DIN, (S2 / KS) / 32, S2 / KS);
  k_redM<<<1024, 256, 0, stream>>>(Mpart, Dm, Mh, Ml, KS);
  // main: y[b][j] = (sum_i u_hi[b][i] * 256M[j][i])/256 + y0[j]
  k_gemm2<2, 1><<<(BATCH / 128) * (DOUT / 128), 256, 0, stream>>>(
      u, nullptr, Mh, Ml, y0, y, DIN, DOUT, DIN / 32, 0);
}